// Round 1
// baseline (27.756 us; speedup 1.0000x reference)
//
#include <hip/hip_runtime.h>
#include <math.h>

#define NP 5
#define NH 64
#define BLK 256

__global__ __launch_bounds__(BLK) void topo_kernel(
    const float* __restrict__ pillars,
    const float* __restrict__ gW1,   // [5][64]
    const float* __restrict__ gb1,   // [64]
    const float* __restrict__ gW2,   // [64]
    const float* __restrict__ gb2,   // [1]
    const float* __restrict__ gLng,  // [5]
    const float* __restrict__ gLnb,  // [5]
    const float* __restrict__ gWc,   // [12]
    const float* __restrict__ gbc,   // [1]
    float* __restrict__ out,
    int n)
{
    __shared__ float sW1[NP*NH];
    __shared__ float sb1[NH];
    __shared__ float sW2[NH];
    __shared__ float sS[NH];          // sum_j W1[j][k]^2
    __shared__ float sGam[NP], sBet[NP], sWc[12];
    __shared__ float sScal[2];        // b2, bc
    __shared__ float sPil[BLK*NP];

    const int t = threadIdx.x;
    for (int i = t; i < NP*NH; i += BLK) sW1[i] = gW1[i];
    if (t < NH) { sb1[t] = gb1[t]; sW2[t] = gW2[t]; }
    if (t < NP) { sGam[t] = gLng[t]; sBet[t] = gLnb[t]; }
    if (t < 12) sWc[t] = gWc[t];
    if (t == 0) { sScal[0] = gb2[0]; sScal[1] = gbc[0]; }
    __syncthreads();
    if (t < NH) {
        float s = 0.f;
        #pragma unroll
        for (int j = 0; j < NP; ++j) { float w = sW1[j*NH + t]; s += w*w; }
        sS[t] = s;
    }

    const long base = (long)blockIdx.x * BLK;
    const long gb = base * NP;
    const long total = (long)n * NP;
    for (int i = t; i < BLK*NP; i += BLK) {
        long gi = gb + i;
        sPil[i] = (gi < total) ? pillars[gi] : 0.f;
    }
    __syncthreads();

    const long sidx = base + t;
    if (sidx >= n) return;

    float raw[NP], p[NP], x[NP];
    #pragma unroll
    for (int j = 0; j < NP; ++j) raw[j] = sPil[t*NP + j];

    // p = clip(nan_to_num(raw, 0.5), 0, 1)
    float mu = 0.f;
    #pragma unroll
    for (int j = 0; j < NP; ++j) {
        float v = raw[j];
        if (!(v == v)) v = 0.5f;          // NaN -> 0.5
        v = fminf(fmaxf(v, 0.f), 1.f);    // clip (handles +/-inf too)
        p[j] = v; mu += v;
    }
    mu *= 0.2f;
    float var = 0.f;
    #pragma unroll
    for (int j = 0; j < NP; ++j) { float d = p[j] - mu; var += d*d; }
    var *= 0.2f;                          // biased variance
    float inv = rsqrtf(var + 1e-5f);
    #pragma unroll
    for (int j = 0; j < NP; ++j) x[j] = (p[j] - mu) * inv * sGam[j] + sBet[j];

    float V = 0.f, tr = 0.f;
    float g0 = 0.f, g1 = 0.f, g2 = 0.f, g3 = 0.f, g4 = 0.f;
    const float INV_SQRT2    = 0.70710678118654752f;
    const float INV_SQRT_2PI = 0.39894228040143268f;
    #pragma unroll 4
    for (int k = 0; k < NH; ++k) {
        float w0 = sW1[k],        w1 = sW1[NH + k], w2 = sW1[2*NH + k];
        float w3 = sW1[3*NH + k], w4 = sW1[4*NH + k];
        float bb = sb1[k];
        float wo = sW2[k];
        float z  = fmaf(p[0],w0, fmaf(p[1],w1, fmaf(p[2],w2, fmaf(p[3],w3, fmaf(p[4],w4, bb)))));
        float zx = fmaf(x[0],w0, fmaf(x[1],w1, fmaf(x[2],w2, fmaf(x[3],w3, fmaf(x[4],w4, bb)))));
        // exact GELU pieces: Phi(z), phi(z)
        float cdf = 0.5f * (1.0f + erff(z * INV_SQRT2));
        float pdf = INV_SQRT_2PI * __expf(-0.5f * z * z);
        V = fmaf(z * cdf, wo, V);                        // gelu(z) * W2
        float d1 = (cdf + z * pdf) * wo;                 // gelu'(z) * W2
        g0 = fmaf(w0, d1, g0); g1 = fmaf(w1, d1, g1); g2 = fmaf(w2, d1, g2);
        g3 = fmaf(w3, d1, g3); g4 = fmaf(w4, d1, g4);
        // Hessian trace term: gelu''(zx) = (2 - zx^2) * phi(zx)
        float pdfx = INV_SQRT_2PI * __expf(-0.5f * zx * zx);
        tr = fmaf(sS[k] * (2.0f - zx*zx) * pdfx, wo, tr);
    }
    V += sScal[0];                // + b2
    float emean = tr * 0.2f;      // mean of eigenvalues = trace/5

    float f[12];
    f[0] = raw[0]; f[1] = raw[1]; f[2] = raw[2]; f[3] = raw[3]; f[4] = raw[4];
    f[5] = g0; f[6] = g1; f[7] = g2; f[8] = g3; f[9] = g4;
    f[10] = V; f[11] = emean;
    float nrm = 0.f;
    #pragma unroll
    for (int i = 0; i < 12; ++i) nrm = fmaf(f[i], f[i], nrm);
    float denom = fmaxf(sqrtf(nrm), 1e-12f);
    float dot = 0.f;
    #pragma unroll
    for (int i = 0; i < 12; ++i) dot = fmaf(f[i], sWc[i], dot);
    float sarg = dot / denom + sScal[1];
    float prob = 1.0f / (1.0f + __expf(-sarg));
    prob = fminf(fmaxf(prob, 0.f), 1.f);
    out[sidx] = prob;
}

extern "C" void kernel_launch(void* const* d_in, const int* in_sizes, int n_in,
                              void* d_out, int out_size, void* d_ws, size_t ws_size,
                              hipStream_t stream) {
    const float* pillars = (const float*)d_in[0];
    const float* W1  = (const float*)d_in[1];
    const float* b1  = (const float*)d_in[2];
    const float* W2  = (const float*)d_in[3];
    const float* b2  = (const float*)d_in[4];
    const float* lng = (const float*)d_in[5];
    const float* lnb = (const float*)d_in[6];
    const float* Wc  = (const float*)d_in[7];
    const float* bc  = (const float*)d_in[8];
    float* out = (float*)d_out;

    const int n = in_sizes[0] / NP;     // 262144
    const int blocks = (n + BLK - 1) / BLK;
    topo_kernel<<<blocks, BLK, 0, stream>>>(
        pillars, W1, b1, W2, b2, lng, lnb, Wc, bc, out, n);
}

// Round 2
// 22.177 us; speedup vs baseline: 1.2516x; 1.2516x over previous
//
#include <hip/hip_runtime.h>
#include <math.h>

#define NP 5
#define NH 64
#define BLK 256

// exp2-domain constants
#define LOG2E       1.44269504088896340736f
#define C_PDF_A     (-0.72134752044448170368f)   // -0.5*log2(e)
#define C_PDF_B     (-1.32574806473616339243f)   // log2(1/sqrt(2*pi))
#define C_CDF0      2.30220840f                  // 2*0.7978845608*log2(e)
#define C_CDF1      0.10294324f                  // 2*0.7978845608*0.044715*log2(e)

__global__ __launch_bounds__(BLK) void topo_kernel(
    const float* __restrict__ pillars,
    const float* __restrict__ gW1,   // [5][64]
    const float* __restrict__ gb1,   // [64]
    const float* __restrict__ gW2,   // [64]
    const float* __restrict__ gb2,   // [1]
    const float* __restrict__ gLng,  // [5]
    const float* __restrict__ gLnb,  // [5]
    const float* __restrict__ gWc,   // [12]
    const float* __restrict__ gbc,   // [1]
    float* __restrict__ out,
    int n)
{
    // packed per-k constants: {w0,w1,w2,w3, w4,b1,wo, 0.2*sumw2*wo}
    __shared__ float sPack[NH * 8];
    __shared__ float sGam[NP], sBet[NP], sWc[12], sScal[2];
    __shared__ float sPil[BLK * NP];

    const int t = threadIdx.x;
    if (t < NH) {
        float w0 = gW1[t],        w1 = gW1[NH + t], w2 = gW1[2*NH + t];
        float w3 = gW1[3*NH + t], w4 = gW1[4*NH + t];
        float bb = gb1[t], wo = gW2[t];
        float s = w0*w0 + w1*w1 + w2*w2 + w3*w3 + w4*w4;
        float* pk = &sPack[t * 8];
        pk[0] = w0; pk[1] = w1; pk[2] = w2; pk[3] = w3;
        pk[4] = w4; pk[5] = bb; pk[6] = wo; pk[7] = 0.2f * s * wo;
    } else if (t >= 64 && t < 64 + NP) {
        int j = t - 64; sGam[j] = gLng[j]; sBet[j] = gLnb[j];
    } else if (t >= 96 && t < 108) {
        int j = t - 96; sWc[j] = gWc[j];
    } else if (t == 128) { sScal[0] = gb2[0]; }
    else if (t == 129)   { sScal[1] = gbc[0]; }

    const long base = (long)blockIdx.x * BLK;
    const long gb = base * NP;
    const long total = (long)n * NP;
    for (int i = t; i < BLK * NP; i += BLK) {
        long gi = gb + i;
        sPil[i] = (gi < total) ? pillars[gi] : 0.f;
    }
    __syncthreads();

    const long sidx = base + t;
    if (sidx >= n) return;

    float raw[NP], p[NP], x[NP];
    #pragma unroll
    for (int j = 0; j < NP; ++j) raw[j] = sPil[t * NP + j];

    // p = clip(nan_to_num(raw, 0.5), 0, 1)
    float mu = 0.f;
    #pragma unroll
    for (int j = 0; j < NP; ++j) {
        float v = raw[j];
        if (!(v == v)) v = 0.5f;
        v = fminf(fmaxf(v, 0.f), 1.f);
        p[j] = v; mu += v;
    }
    mu *= 0.2f;
    float var = 0.f;
    #pragma unroll
    for (int j = 0; j < NP; ++j) { float d = p[j] - mu; var += d * d; }
    var *= 0.2f;
    float inv = rsqrtf(var + 1e-5f);
    #pragma unroll
    for (int j = 0; j < NP; ++j) x[j] = (p[j] - mu) * inv * sGam[j] + sBet[j];

    float V = 0.f, tr = 0.f;
    float g0 = 0.f, g1 = 0.f, g2 = 0.f, g3 = 0.f, g4 = 0.f;

    const float4* pk4 = reinterpret_cast<const float4*>(sPack);
    #pragma unroll 8
    for (int k = 0; k < NH; ++k) {
        float4 a = pk4[2 * k];
        float4 b = pk4[2 * k + 1];
        float w0 = a.x, w1 = a.y, w2 = a.z, w3 = a.w;
        float w4 = b.x, bb = b.y, wo = b.z, sSw = b.w;

        float z  = fmaf(p[0],w0, fmaf(p[1],w1, fmaf(p[2],w2, fmaf(p[3],w3, fmaf(p[4],w4, bb)))));
        float zx = fmaf(x[0],w0, fmaf(x[1],w1, fmaf(x[2],w2, fmaf(x[3],w3, fmaf(x[4],w4, bb)))));

        float tz = z * z;
        float tx = zx * zx;

        // Phi(z) ~ sigmoid(2*0.79788456*(z + 0.044715 z^3)), exp2 domain
        float ya = z * fmaf(tz, -C_CDF1, -C_CDF0);           // -2y*log2e
        float e  = __builtin_amdgcn_exp2f(ya);
        float cdf = __builtin_amdgcn_rcpf(1.0f + e);

        // phi(z)/sqrt(2pi) folded: exp2(-0.5*log2e*z^2 + log2(1/sqrt(2pi)))
        float pdf = __builtin_amdgcn_exp2f(fmaf(tz, C_PDF_A, C_PDF_B));

        V = fmaf(z * cdf, wo, V);                            // gelu(z)*W2
        float d1 = fmaf(z, pdf, cdf) * wo;                   // gelu'(z)*W2
        g0 = fmaf(w0, d1, g0); g1 = fmaf(w1, d1, g1); g2 = fmaf(w2, d1, g2);
        g3 = fmaf(w3, d1, g3); g4 = fmaf(w4, d1, g4);

        // trace: 0.2*sum(w^2)*wo * (2 - zx^2) * phi(zx)
        float pdfx = __builtin_amdgcn_exp2f(fmaf(tx, C_PDF_A, C_PDF_B));
        tr = fmaf(sSw * (2.0f - tx), pdfx, tr);
    }
    V += sScal[0];                 // + b2
    float emean = tr;              // 0.2 already folded into sSw

    float f[12];
    f[0] = raw[0]; f[1] = raw[1]; f[2] = raw[2]; f[3] = raw[3]; f[4] = raw[4];
    f[5] = g0; f[6] = g1; f[7] = g2; f[8] = g3; f[9] = g4;
    f[10] = V; f[11] = emean;
    float nrm = 0.f;
    #pragma unroll
    for (int i = 0; i < 12; ++i) nrm = fmaf(f[i], f[i], nrm);
    float denom = fmaxf(sqrtf(nrm), 1e-12f);
    float dot = 0.f;
    #pragma unroll
    for (int i = 0; i < 12; ++i) dot = fmaf(f[i], sWc[i], dot);
    float sarg = dot / denom + sScal[1];
    float es = __builtin_amdgcn_exp2f(-sarg * LOG2E);
    float prob = __builtin_amdgcn_rcpf(1.0f + es);
    prob = fminf(fmaxf(prob, 0.f), 1.f);
    out[sidx] = prob;
}

extern "C" void kernel_launch(void* const* d_in, const int* in_sizes, int n_in,
                              void* d_out, int out_size, void* d_ws, size_t ws_size,
                              hipStream_t stream) {
    const float* pillars = (const float*)d_in[0];
    const float* W1  = (const float*)d_in[1];
    const float* b1  = (const float*)d_in[2];
    const float* W2  = (const float*)d_in[3];
    const float* b2  = (const float*)d_in[4];
    const float* lng = (const float*)d_in[5];
    const float* lnb = (const float*)d_in[6];
    const float* Wc  = (const float*)d_in[7];
    const float* bc  = (const float*)d_in[8];
    float* out = (float*)d_out;

    const int n = in_sizes[0] / NP;     // 262144
    const int blocks = (n + BLK - 1) / BLK;
    topo_kernel<<<blocks, BLK, 0, stream>>>(
        pillars, W1, b1, W2, b2, lng, lnb, Wc, bc, out, n);
}

// Round 3
// 19.757 us; speedup vs baseline: 1.4049x; 1.1225x over previous
//
#include <hip/hip_runtime.h>
#include <math.h>

#define NP 5
#define NH 64
#define NPAIR 32
#define BLK 256

typedef float f32x2 __attribute__((ext_vector_type(2)));
typedef float f32x4 __attribute__((ext_vector_type(4)));

#define LOG2E 1.44269504088896340736f
// -2y(z)*log2(e) = z*(-C_CDF0 - C_CDF1*z^2),  2y = 1.5957691*(z + 0.044715 z^3)
#define C_CDF0 2.30220840f
#define C_CDF1 0.10294324f
// d(2y)/dz = C_G2A + C_G2B*z^2
#define C_G2A 1.59576912f
#define C_G2B 0.21406460f
// phi(z)=exp2(C_PDF_A*z^2 + C_PDF_B)  (exact Gaussian, 1/sqrt(2pi) folded)
#define C_PDF_A (-0.72134752f)
#define C_PDF_B (-1.32574806f)

__global__ __launch_bounds__(BLK) void topo_kernel(
    const float* __restrict__ pillars,
    const float* __restrict__ gW1,   // [5][64]
    const float* __restrict__ gb1,   // [64]
    const float* __restrict__ gW2,   // [64]
    const float* __restrict__ gb2,   // [1]
    const float* __restrict__ gLng,  // [5]
    const float* __restrict__ gLnb,  // [5]
    const float* __restrict__ gWc,   // [12]
    const float* __restrict__ gbc,   // [1]
    float* __restrict__ out,
    int n)
{
    // pair-packed per-k constants, 16 floats per pair pp (k=2pp, 2pp+1):
    // [0..3]={w0.lo,w0.hi,w1.lo,w1.hi} [4..7]={w2*,w3*} [8..11]={w4*,b1*}
    // [12..15]={wo.lo,wo.hi,sw.lo,sw.hi}   sw = 0.2*sum(w^2)*wo
    __shared__ float sPack[NPAIR * 16];
    __shared__ float sGam[NP], sBet[NP], sWc[12], sScal[2];
    __shared__ float sPil[BLK * NP];

    const int t = threadIdx.x;
    if (t < NH) {
        float w0 = gW1[t],        w1 = gW1[NH + t], w2 = gW1[2*NH + t];
        float w3 = gW1[3*NH + t], w4 = gW1[4*NH + t];
        float bb = gb1[t], wo = gW2[t];
        float s  = w0*w0 + w1*w1 + w2*w2 + w3*w3 + w4*w4;
        float sw = 0.2f * s * wo;
        const int base = (t >> 1) * 16 + (t & 1);
        sPack[base + 0]  = w0;  sPack[base + 2]  = w1;
        sPack[base + 4]  = w2;  sPack[base + 6]  = w3;
        sPack[base + 8]  = w4;  sPack[base + 10] = bb;
        sPack[base + 12] = wo;  sPack[base + 14] = sw;
    } else if (t >= 64 && t < 64 + NP) {
        int j = t - 64; sGam[j] = gLng[j]; sBet[j] = gLnb[j];
    } else if (t >= 96 && t < 108) {
        int j = t - 96; sWc[j] = gWc[j];
    } else if (t == 128) { sScal[0] = gb2[0]; }
    else if (t == 129)   { sScal[1] = gbc[0]; }

    const long base = (long)blockIdx.x * BLK;
    const long gbp = base * NP;
    const long total = (long)n * NP;
    for (int i = t; i < BLK * NP; i += BLK) {
        long gi = gbp + i;
        sPil[i] = (gi < total) ? pillars[gi] : 0.f;
    }
    __syncthreads();

    const long sidx = base + t;
    if (sidx >= n) return;

    float raw[NP], p[NP], x[NP];
    #pragma unroll
    for (int j = 0; j < NP; ++j) raw[j] = sPil[t * NP + j];

    float mu = 0.f;
    #pragma unroll
    for (int j = 0; j < NP; ++j) {
        float v = raw[j];
        if (!(v == v)) v = 0.5f;          // NaN -> 0.5
        v = fminf(fmaxf(v, 0.f), 1.f);    // clip
        p[j] = v; mu += v;
    }
    mu *= 0.2f;
    float var = 0.f;
    #pragma unroll
    for (int j = 0; j < NP; ++j) { float d = p[j] - mu; var += d * d; }
    var *= 0.2f;
    float inv = rsqrtf(var + 1e-5f);
    #pragma unroll
    for (int j = 0; j < NP; ++j) x[j] = (p[j] - mu) * inv * sGam[j] + sBet[j];

    // splat to float2 lanes (pair of k's)
    f32x2 P[NP], X[NP];
    #pragma unroll
    for (int j = 0; j < NP; ++j) { P[j] = (f32x2){p[j], p[j]}; X[j] = (f32x2){x[j], x[j]}; }

    const f32x2 one = {1.f, 1.f}, two = {2.f, 2.f};
    const f32x2 cC0 = {-C_CDF0, -C_CDF0}, cC1 = {-C_CDF1, -C_CDF1};
    const f32x2 cGA = {C_G2A, C_G2A},     cGB = {C_G2B, C_G2B};
    const f32x2 cPA = {C_PDF_A, C_PDF_A}, cPB = {C_PDF_B, C_PDF_B};

    f32x2 V2 = {0.f,0.f}, TR = {0.f,0.f};
    f32x2 G0 = {0.f,0.f}, G1 = {0.f,0.f}, G2 = {0.f,0.f}, G3 = {0.f,0.f}, G4 = {0.f,0.f};

    const f32x4* pk4 = reinterpret_cast<const f32x4*>(sPack);
    #pragma unroll 4
    for (int pp = 0; pp < NPAIR; ++pp) {
        f32x4 q0 = pk4[pp * 4 + 0];
        f32x4 q1 = pk4[pp * 4 + 1];
        f32x4 q2 = pk4[pp * 4 + 2];
        f32x4 q3 = pk4[pp * 4 + 3];
        f32x2 w0 = q0.xy, w1 = q0.zw;
        f32x2 w2 = q1.xy, w3 = q1.zw;
        f32x2 w4 = q2.xy, bb = q2.zw;
        f32x2 wo = q3.xy, sw = q3.zw;

        f32x2 z  = P[0]*w0 + (P[1]*w1 + (P[2]*w2 + (P[3]*w3 + (P[4]*w4 + bb))));
        f32x2 zx = X[0]*w0 + (X[1]*w1 + (X[2]*w2 + (X[3]*w3 + (X[4]*w4 + bb))));

        f32x2 tz = z * z;
        f32x2 tx = zx * zx;

        // sigma(2y) via exp2
        f32x2 ya = z * (tz * cC1 + cC0);
        f32x2 e;
        e.x = __builtin_amdgcn_exp2f(ya.x);
        e.y = __builtin_amdgcn_exp2f(ya.y);
        f32x2 ope = e + one;
        f32x2 s;
        s.x = __builtin_amdgcn_rcpf(ope.x);
        s.y = __builtin_amdgcn_rcpf(ope.y);

        V2 = (z * s) * wo + V2;                       // gelu(z)*W2
        f32x2 u   = s - s * s;                        // sigma*(1-sigma)
        f32x2 g2p = tz * cGB + cGA;                   // d(2y)/dz
        f32x2 d1  = ((z * u) * g2p + s) * wo;         // gelu'(z)*W2
        G0 = w0 * d1 + G0; G1 = w1 * d1 + G1; G2 = w2 * d1 + G2;
        G3 = w3 * d1 + G3; G4 = w4 * d1 + G4;

        // trace: sw*(2 - zx^2)*phi(zx)   (phi exact, exp2 domain)
        f32x2 pa = tx * cPA + cPB;
        f32x2 ph;
        ph.x = __builtin_amdgcn_exp2f(pa.x);
        ph.y = __builtin_amdgcn_exp2f(pa.y);
        TR = (sw * (two - tx)) * ph + TR;
    }

    float V = V2.x + V2.y + sScal[0];
    float emean = TR.x + TR.y;          // 0.2 folded into sw

    float f[12];
    f[0] = raw[0]; f[1] = raw[1]; f[2] = raw[2]; f[3] = raw[3]; f[4] = raw[4];
    f[5] = G0.x + G0.y; f[6] = G1.x + G1.y; f[7] = G2.x + G2.y;
    f[8] = G3.x + G3.y; f[9] = G4.x + G4.y;
    f[10] = V; f[11] = emean;

    float nrm = 0.f;
    #pragma unroll
    for (int i = 0; i < 12; ++i) nrm = fmaf(f[i], f[i], nrm);
    float denom = fmaxf(sqrtf(nrm), 1e-12f);
    float dot = 0.f;
    #pragma unroll
    for (int i = 0; i < 12; ++i) dot = fmaf(f[i], sWc[i], dot);
    float sarg = dot * __builtin_amdgcn_rcpf(denom) + sScal[1];
    float es = __builtin_amdgcn_exp2f(-sarg * LOG2E);
    float prob = __builtin_amdgcn_rcpf(1.0f + es);
    prob = fminf(fmaxf(prob, 0.f), 1.f);
    out[sidx] = prob;
}

extern "C" void kernel_launch(void* const* d_in, const int* in_sizes, int n_in,
                              void* d_out, int out_size, void* d_ws, size_t ws_size,
                              hipStream_t stream) {
    const float* pillars = (const float*)d_in[0];
    const float* W1  = (const float*)d_in[1];
    const float* b1  = (const float*)d_in[2];
    const float* W2  = (const float*)d_in[3];
    const float* b2  = (const float*)d_in[4];
    const float* lng = (const float*)d_in[5];
    const float* lnb = (const float*)d_in[6];
    const float* Wc  = (const float*)d_in[7];
    const float* bc  = (const float*)d_in[8];
    float* out = (float*)d_out;

    const int n = in_sizes[0] / NP;     // 262144
    const int blocks = (n + BLK - 1) / BLK;
    topo_kernel<<<blocks, BLK, 0, stream>>>(
        pillars, W1, b1, W2, b2, lng, lnb, Wc, bc, out, n);
}